// Round 4
// baseline (381.495 us; speedup 1.0000x reference)
//
#include <hip/hip_runtime.h>
#include <stdint.h>

#define B_  128
#define S_  512
#define D_  768
#define T_  51
#define NI  26
#define NS  122
#define M_TOT (B_ * T_)   // 6528

#define APAD 40   // padded row (shorts): 80B stride, 16B-aligned, 2-way banks max

typedef __bf16 bf16x8 __attribute__((ext_vector_type(8)));
typedef float  f32x4  __attribute__((ext_vector_type(4)));

__device__ __forceinline__ unsigned short f2bf(float f) {
    union { float f; uint32_t u; } v; v.f = f;
    uint32_t u = v.u + 0x7FFF + ((v.u >> 16) & 1);   // RNE
    return (unsigned short)(u >> 16);
}

// ---------------------------------------------------------------------------
// Kernel 1: intent head  res_id[b,n] = res[b,:] @ W_id[:,n] + b_id[n]
// ---------------------------------------------------------------------------
__global__ void k_intent(const float* __restrict__ res,
                         const float* __restrict__ W_id,
                         const float* __restrict__ b_id,
                         float* __restrict__ out) {
    int b = blockIdx.x;
    int n = threadIdx.x;
    if (n >= NI) return;
    float a = b_id[n];
    const float* rb = res + b * D_;
    for (int d = 0; d < D_; ++d) a += rb[d] * W_id[d * NI + n];
    out[b * NI + n] = a;
}

// ---------------------------------------------------------------------------
// Kernel 2: QW[m,:] = bf16( res_all[b, start, :] ) @ bf16( W_attn )
//   M=6528, N=768, K=768.  64x64 block tile, 4 waves of 32x32, 16x16x32 MFMA.
//   Gather of A rows fused into staging.
// ---------------------------------------------------------------------------
__global__ __launch_bounds__(256) void k_qw(
    const float* __restrict__ res_all, const int* __restrict__ tsi,
    const float* __restrict__ W_attn, float* __restrict__ QW)
{
    __shared__ __align__(16) unsigned short As[64][APAD];  // A[r][k]
    __shared__ __align__(16) unsigned short Bs[64][APAD];  // B^T: Bs[n][k]

    const int tid  = threadIdx.x;
    const int lane = tid & 63;
    const int wave = tid >> 6;
    const int m0 = blockIdx.y * 64;
    const int n0 = blockIdx.x * 64;

    // A staging: thread -> row (tid>>2), k-chunk (tid&3)*8
    const int ar  = tid >> 2;
    const int akc = (tid & 3) * 8;
    const int am  = m0 + ar;
    const int ab  = am / T_;
    const int astart = tsi[am];
    const size_t abase = ((size_t)ab * S_ + astart) * D_;

    // B staging: thread -> k-row (tid>>3), n-chunk (tid&7)*8 (transposed store)
    const int bk  = tid >> 3;
    const int bnc = (tid & 7) * 8;

    const int wm = (wave & 1) * 32;
    const int wn = (wave >> 1) * 32;
    const int fr = lane & 15;          // fragment row/col index
    const int fk = (lane >> 4) * 8;    // fragment k offset

    f32x4 acc[2][2] = {};

    for (int k0 = 0; k0 < D_; k0 += 32) {
        // ---- stage A (gathered g0 rows, f32 -> bf16) ----
        float4 a0 = *(const float4*)(res_all + abase + k0 + akc);
        float4 a1 = *(const float4*)(res_all + abase + k0 + akc + 4);
        unsigned short* ap = &As[ar][akc];
        ap[0] = f2bf(a0.x); ap[1] = f2bf(a0.y); ap[2] = f2bf(a0.z); ap[3] = f2bf(a0.w);
        ap[4] = f2bf(a1.x); ap[5] = f2bf(a1.y); ap[6] = f2bf(a1.z); ap[7] = f2bf(a1.w);
        // ---- stage B (W_attn, transposed to [n][k]) ----
        const float* wp = W_attn + (size_t)(k0 + bk) * D_ + n0 + bnc;
        float4 b0 = *(const float4*)(wp);
        float4 b1 = *(const float4*)(wp + 4);
        Bs[bnc+0][bk] = f2bf(b0.x); Bs[bnc+1][bk] = f2bf(b0.y);
        Bs[bnc+2][bk] = f2bf(b0.z); Bs[bnc+3][bk] = f2bf(b0.w);
        Bs[bnc+4][bk] = f2bf(b1.x); Bs[bnc+5][bk] = f2bf(b1.y);
        Bs[bnc+6][bk] = f2bf(b1.z); Bs[bnc+7][bk] = f2bf(b1.w);
        __syncthreads();

        bf16x8 a_frag0 = *(const bf16x8*)&As[wm + fr][fk];
        bf16x8 a_frag1 = *(const bf16x8*)&As[wm + 16 + fr][fk];
        bf16x8 b_frag0 = *(const bf16x8*)&Bs[wn + fr][fk];
        bf16x8 b_frag1 = *(const bf16x8*)&Bs[wn + 16 + fr][fk];

        acc[0][0] = __builtin_amdgcn_mfma_f32_16x16x32_bf16(a_frag0, b_frag0, acc[0][0], 0, 0, 0);
        acc[0][1] = __builtin_amdgcn_mfma_f32_16x16x32_bf16(a_frag0, b_frag1, acc[0][1], 0, 0, 0);
        acc[1][0] = __builtin_amdgcn_mfma_f32_16x16x32_bf16(a_frag1, b_frag0, acc[1][0], 0, 0, 0);
        acc[1][1] = __builtin_amdgcn_mfma_f32_16x16x32_bf16(a_frag1, b_frag1, acc[1][1], 0, 0, 0);
        __syncthreads();
    }

    // C write: row = (lane>>4)*4 + r, col = lane&15 within each 16x16 frag
    for (int mf = 0; mf < 2; ++mf)
        for (int nf = 0; nf < 2; ++nf)
            for (int r = 0; r < 4; ++r) {
                int row = m0 + wm + mf * 16 + (lane >> 4) * 4 + r;
                int col = n0 + wn + nf * 16 + (lane & 15);
                QW[(size_t)row * D_ + col] = acc[mf][nf][r];
            }
}

// ---------------------------------------------------------------------------
// Kernel 3: per 8 rows — scores from QW, softmax, word, slot head.
// ---------------------------------------------------------------------------
__global__ __launch_bounds__(256) void k_word_slot(
    const float* __restrict__ res_all, const float* __restrict__ res,
    const int* __restrict__ tsi, const int* __restrict__ slen,
    const float* __restrict__ QW, const float* __restrict__ W_slot,
    const float* __restrict__ b_slot, float* __restrict__ res_sf)
{
    __shared__ float word[8][D_];        // 24 KB
    __shared__ float part[2][8][128];    // 8 KB
    __shared__ float s_w0[8], s_w1[8];
    __shared__ size_t s_off0[8], s_off1[8];
    __shared__ int s_bres[8];

    const int tid  = threadIdx.x;
    const int lane = tid & 63;
    const int wave = tid >> 6;
    const int m0 = blockIdx.x * 8;

    // ---- phase 1: bilinear scores + softmax weights (2 rows per wave) ----
    for (int rr = 0; rr < 2; ++rr) {
        int r = wave * 2 + rr;
        int m = m0 + r;
        int b = m / T_;
        int start = tsi[m];
        int len   = slen[m];
        size_t off0 = ((size_t)b * S_ + start) * D_;
        size_t off1 = off0 + (size_t)len * D_;
        const float* q = QW + (size_t)m * D_;
        float s0 = 0.f, s1 = 0.f;
        for (int it = 0; it < D_ / 64; ++it) {
            int e = lane + it * 64;
            float qv = q[e];
            s0 += qv * res_all[off0 + e];
            s1 += qv * res_all[off1 + e];
        }
        for (int msk = 32; msk >= 1; msk >>= 1) {
            s0 += __shfl_xor(s0, msk, 64);
            s1 += __shfl_xor(s1, msk, 64);
        }
        if (lane == 0) {
            const float scale = 0.036084391824351615f;  // 768^-0.5
            float w1 = (len == 1) ? 0.f
                                  : 1.f / (1.f + expf((s0 - s1) * scale));
            s_w0[r] = 1.f - w1;
            s_w1[r] = w1;
            s_off0[r] = off0;
            s_off1[r] = off1;
            s_bres[r] = b * D_;
        }
    }
    __syncthreads();

    // ---- phase 2: word rows into LDS ----
    for (int r = 0; r < 8; ++r) {
        float w0 = s_w0[r], w1 = s_w1[r];
        size_t o0 = s_off0[r], o1 = s_off1[r];
        int rb = s_bres[r];
        for (int e = tid; e < D_; e += 256)
            word[r][e] = w0 * res_all[o0 + e] + w1 * res_all[o1 + e] + res[rb + e];
    }
    __syncthreads();

    // ---- phase 3: slot head, k-outer so W_slot is read once per block ----
    int h = tid >> 7, col = tid & 127;
    float acc[8] = {0.f, 0.f, 0.f, 0.f, 0.f, 0.f, 0.f, 0.f};
    if (col < NS) {
        for (int k = h * 384; k < h * 384 + 384; ++k) {
            float wv = W_slot[(size_t)k * NS + col];
            #pragma unroll
            for (int r = 0; r < 8; ++r) acc[r] += word[r][k] * wv;
        }
    }
    #pragma unroll
    for (int r = 0; r < 8; ++r) part[h][r][col] = acc[r];
    __syncthreads();

    if (tid < NS) {
        float bs = b_slot[tid];
        for (int r = 0; r < 8; ++r)
            res_sf[(size_t)(m0 + r) * NS + tid] = bs + part[0][r][tid] + part[1][r][tid];
    }
}

// ---------------------------------------------------------------------------
extern "C" void kernel_launch(void* const* d_in, const int* in_sizes, int n_in,
                              void* d_out, int out_size, void* d_ws, size_t ws_size,
                              hipStream_t stream) {
    const float* res_all = (const float*)d_in[0];
    const float* res     = (const float*)d_in[1];
    const int*   tsi     = (const int*)d_in[2];
    const int*   slen    = (const int*)d_in[3];
    const float* W_attn  = (const float*)d_in[4];
    const float* W_id    = (const float*)d_in[5];
    const float* b_id    = (const float*)d_in[6];
    const float* W_slot  = (const float*)d_in[7];
    const float* b_slot  = (const float*)d_in[8];

    float* out    = (float*)d_out;
    float* res_id = out;                 // [128, 26]
    float* res_sf = out + B_ * NI;       // [6528, 122]
    float* QW     = (float*)d_ws;        // [6528, 768] f32 = 19.1 MB

    k_intent<<<dim3(B_), dim3(64), 0, stream>>>(res, W_id, b_id, res_id);
    k_qw<<<dim3(D_ / 64, M_TOT / 64), dim3(256), 0, stream>>>(res_all, tsi, W_attn, QW);
    k_word_slot<<<dim3(M_TOT / 8), dim3(256), 0, stream>>>(res_all, res, tsi, slen,
                                                           QW, W_slot, b_slot, res_sf);
}

// Round 14
// 362.666 us; speedup vs baseline: 1.0519x; 1.0519x over previous
//
#include <hip/hip_runtime.h>
#include <stdint.h>

#define B_  128
#define S_  512
#define D_  768
#define T_  51
#define NI  26
#define NS  122
#define M_TOT (B_ * T_)   // 6528

#define BK    64
#define LROW  72          // LDS row stride in shorts: 144B, 16B-aligned, 2-way max on frag reads

typedef __bf16 bf16x8 __attribute__((ext_vector_type(8)));
typedef float  f32x4  __attribute__((ext_vector_type(4)));
typedef unsigned short u16x8 __attribute__((ext_vector_type(8)));

__device__ __forceinline__ unsigned short f2bf(float f) {
    __bf16 h = (__bf16)f;                 // RNE; compiler may pack to v_cvt_pk_bf16_f32
    union { __bf16 h; unsigned short u; } v; v.h = h;
    return v.u;
}

// ---------------------------------------------------------------------------
// Kernel 0: WT[n][k] = bf16(W_attn[k][n])  (768x768 transpose + convert)
// ---------------------------------------------------------------------------
__global__ __launch_bounds__(256) void k_prep(const float* __restrict__ W,
                                              unsigned short* __restrict__ WT) {
    __shared__ float t[32][33];
    const int tx = threadIdx.x, ty = threadIdx.y;
    const int n0 = blockIdx.x * 32, k0 = blockIdx.y * 32;
    #pragma unroll
    for (int i = 0; i < 4; ++i)
        t[ty + i * 8][tx] = W[(size_t)(k0 + ty + i * 8) * D_ + n0 + tx];
    __syncthreads();
    #pragma unroll
    for (int i = 0; i < 4; ++i)
        WT[(size_t)(n0 + ty + i * 8) * D_ + k0 + tx] = f2bf(t[tx][ty + i * 8]);
}

// ---------------------------------------------------------------------------
// Kernel 1: intent head  res_id[b,n] = res[b,:] @ W_id[:,n] + b_id[n]
// ---------------------------------------------------------------------------
__global__ void k_intent(const float* __restrict__ res,
                         const float* __restrict__ W_id,
                         const float* __restrict__ b_id,
                         float* __restrict__ out) {
    int b = blockIdx.x;
    int n = threadIdx.x;
    if (n >= NI) return;
    float a = b_id[n];
    const float* rb = res + b * D_;
    for (int d = 0; d < D_; ++d) a += rb[d] * W_id[d * NI + n];
    out[b * NI + n] = a;
}

// ---------------------------------------------------------------------------
// Kernel 2: QW = bf16(gather g0) @ bf16(W_attn).  M=6528,N=768,K=768.
//   64x64 tile, BK=64, 4 waves of 32x32, 16x16x32 MFMA.
//   B comes pre-transposed/converted (WT) -> conflict-free b128 staging.
// ---------------------------------------------------------------------------
__global__ __launch_bounds__(256) void k_qw(
    const float* __restrict__ res_all, const int* __restrict__ tsi,
    const unsigned short* __restrict__ WT, float* __restrict__ QW)
{
    __shared__ __align__(16) unsigned short As[64][LROW];
    __shared__ __align__(16) unsigned short Bs[64][LROW];

    const int tid  = threadIdx.x;
    const int lane = tid & 63;
    const int wave = tid >> 6;
    const int m0 = blockIdx.y * 64;
    const int n0 = blockIdx.x * 64;

    // staging map: row = tid>>2, 16-short chunk = (tid&3)*16
    const int srow = tid >> 2;
    const int skc  = (tid & 3) * 16;
    const int am   = m0 + srow;
    const int ab   = am / T_;
    const size_t abase = ((size_t)ab * S_ + tsi[am]) * D_;
    const unsigned short* wtrow = WT + (size_t)(n0 + srow) * D_;

    const int wm = (wave & 1) * 32;
    const int wn = (wave >> 1) * 32;
    const int fr = lane & 15;
    const int fq = lane >> 4;            // 0..3

    f32x4 acc[2][2] = {};

    for (int k0 = 0; k0 < D_; k0 += BK) {
        // ---- stage A: 4x float4 -> 16 bf16 -> 2x ds_write_b128 ----
        unsigned short tmp[16];
        #pragma unroll
        for (int j = 0; j < 4; ++j) {
            float4 v = *(const float4*)(res_all + abase + k0 + skc + j * 4);
            tmp[j*4+0] = f2bf(v.x); tmp[j*4+1] = f2bf(v.y);
            tmp[j*4+2] = f2bf(v.z); tmp[j*4+3] = f2bf(v.w);
        }
        *(u16x8*)&As[srow][skc]     = *(u16x8*)&tmp[0];
        *(u16x8*)&As[srow][skc + 8] = *(u16x8*)&tmp[8];
        // ---- stage B: 2x 16B row loads -> 2x ds_write_b128 ----
        *(u16x8*)&Bs[srow][skc]     = *(const u16x8*)(wtrow + k0 + skc);
        *(u16x8*)&Bs[srow][skc + 8] = *(const u16x8*)(wtrow + k0 + skc + 8);
        __syncthreads();

        #pragma unroll
        for (int ks = 0; ks < 2; ++ks) {
            const int fk = ks * 32 + fq * 8;
            bf16x8 a0 = *(const bf16x8*)&As[wm + fr][fk];
            bf16x8 a1 = *(const bf16x8*)&As[wm + 16 + fr][fk];
            bf16x8 b0 = *(const bf16x8*)&Bs[wn + fr][fk];
            bf16x8 b1 = *(const bf16x8*)&Bs[wn + 16 + fr][fk];
            acc[0][0] = __builtin_amdgcn_mfma_f32_16x16x32_bf16(a0, b0, acc[0][0], 0, 0, 0);
            acc[0][1] = __builtin_amdgcn_mfma_f32_16x16x32_bf16(a0, b1, acc[0][1], 0, 0, 0);
            acc[1][0] = __builtin_amdgcn_mfma_f32_16x16x32_bf16(a1, b0, acc[1][0], 0, 0, 0);
            acc[1][1] = __builtin_amdgcn_mfma_f32_16x16x32_bf16(a1, b1, acc[1][1], 0, 0, 0);
        }
        __syncthreads();
    }

    // C/D: col=lane&15, row=(lane>>4)*4+r  (m89-verified)
    #pragma unroll
    for (int mf = 0; mf < 2; ++mf)
        #pragma unroll
        for (int nf = 0; nf < 2; ++nf)
            #pragma unroll
            for (int r = 0; r < 4; ++r) {
                int row = m0 + wm + mf * 16 + fq * 4 + r;
                int col = n0 + wn + nf * 16 + fr;
                QW[(size_t)row * D_ + col] = acc[mf][nf][r];
            }
}

// ---------------------------------------------------------------------------
// Kernel 3: per 8 rows — scores from QW, softmax, word, slot head.
// ---------------------------------------------------------------------------
__global__ __launch_bounds__(256) void k_word_slot(
    const float* __restrict__ res_all, const float* __restrict__ res,
    const int* __restrict__ tsi, const int* __restrict__ slen,
    const float* __restrict__ QW, const float* __restrict__ W_slot,
    const float* __restrict__ b_slot, float* __restrict__ res_sf)
{
    __shared__ float word[8][D_];        // 24 KB
    __shared__ float part[2][8][128];    // 8 KB
    __shared__ float s_w0[8], s_w1[8];
    __shared__ size_t s_off0[8], s_off1[8];
    __shared__ int s_bres[8];

    const int tid  = threadIdx.x;
    const int lane = tid & 63;
    const int wave = tid >> 6;
    const int m0 = blockIdx.x * 8;

    // ---- phase 1: bilinear scores + softmax weights (2 rows per wave) ----
    for (int rr = 0; rr < 2; ++rr) {
        int r = wave * 2 + rr;
        int m = m0 + r;
        int b = m / T_;
        int start = tsi[m];
        int len   = slen[m];
        size_t off0 = ((size_t)b * S_ + start) * D_;
        size_t off1 = off0 + (size_t)len * D_;
        const float4* q4 = (const float4*)(QW + (size_t)m * D_);
        const float4* r0 = (const float4*)(res_all + off0);
        const float4* r1 = (const float4*)(res_all + off1);
        float s0 = 0.f, s1 = 0.f;
        #pragma unroll
        for (int it = 0; it < 3; ++it) {       // 192 float4 per row
            int e = lane + it * 64;
            float4 qv = q4[e], a = r0[e], bb = r1[e];
            s0 += qv.x*a.x  + qv.y*a.y  + qv.z*a.z  + qv.w*a.w;
            s1 += qv.x*bb.x + qv.y*bb.y + qv.z*bb.z + qv.w*bb.w;
        }
        for (int msk = 32; msk >= 1; msk >>= 1) {
            s0 += __shfl_xor(s0, msk, 64);
            s1 += __shfl_xor(s1, msk, 64);
        }
        if (lane == 0) {
            const float scale = 0.036084391824351615f;  // 768^-0.5
            float w1 = (len == 1) ? 0.f
                                  : 1.f / (1.f + expf((s0 - s1) * scale));
            s_w0[r] = 1.f - w1;
            s_w1[r] = w1;
            s_off0[r] = off0;
            s_off1[r] = off1;
            s_bres[r] = b * D_;
        }
    }
    __syncthreads();

    // ---- phase 2: word rows into LDS (float4) ----
    #pragma unroll
    for (int i = 0; i < 6; ++i) {              // 8 rows * 192 f4 = 1536 / 256
        int f = tid + i * 256;
        int r = f / 192;
        int e = f - r * 192;
        float w0 = s_w0[r], w1 = s_w1[r];
        const float4 a = ((const float4*)(res_all + s_off0[r]))[e];
        const float4 b = ((const float4*)(res_all + s_off1[r]))[e];
        const float4 c = ((const float4*)(res + s_bres[r]))[e];
        float4 o;
        o.x = w0*a.x + w1*b.x + c.x;
        o.y = w0*a.y + w1*b.y + c.y;
        o.z = w0*a.z + w1*b.z + c.z;
        o.w = w0*a.w + w1*b.w + c.w;
        *(float4*)&word[r][e * 4] = o;
    }
    __syncthreads();

    // ---- phase 3: slot head, k-outer so W_slot is read once per block ----
    int h = tid >> 7, col = tid & 127;
    float acc[8] = {0.f, 0.f, 0.f, 0.f, 0.f, 0.f, 0.f, 0.f};
    if (col < NS) {
        for (int k = h * 384; k < h * 384 + 384; ++k) {
            float wv = W_slot[(size_t)k * NS + col];
            #pragma unroll
            for (int r = 0; r < 8; ++r) acc[r] += word[r][k] * wv;
        }
    }
    #pragma unroll
    for (int r = 0; r < 8; ++r) part[h][r][col] = acc[r];
    __syncthreads();

    if (tid < NS) {
        float bs = b_slot[tid];
        for (int r = 0; r < 8; ++r)
            res_sf[(size_t)(m0 + r) * NS + tid] = bs + part[0][r][tid] + part[1][r][tid];
    }
}

// ---------------------------------------------------------------------------
extern "C" void kernel_launch(void* const* d_in, const int* in_sizes, int n_in,
                              void* d_out, int out_size, void* d_ws, size_t ws_size,
                              hipStream_t stream) {
    const float* res_all = (const float*)d_in[0];
    const float* res     = (const float*)d_in[1];
    const int*   tsi     = (const int*)d_in[2];
    const int*   slen    = (const int*)d_in[3];
    const float* W_attn  = (const float*)d_in[4];
    const float* W_id    = (const float*)d_in[5];
    const float* b_id    = (const float*)d_in[6];
    const float* W_slot  = (const float*)d_in[7];
    const float* b_slot  = (const float*)d_in[8];

    float* out    = (float*)d_out;
    float* res_id = out;                 // [128, 26]
    float* res_sf = out + B_ * NI;       // [6528, 122]
    float* QW     = (float*)d_ws;                                   // 19.1 MB
    unsigned short* WT = (unsigned short*)((char*)d_ws + (32u << 20)); // 1.1 MB @ +32MB

    k_prep<<<dim3(D_ / 32, D_ / 32), dim3(32, 8), 0, stream>>>(W_attn, WT);
    k_intent<<<dim3(B_), dim3(64), 0, stream>>>(res, W_id, b_id, res_id);
    k_qw<<<dim3(D_ / 64, M_TOT / 64), dim3(256), 0, stream>>>(res_all, tsi, WT, QW);
    k_word_slot<<<dim3(M_TOT / 8), dim3(256), 0, stream>>>(res_all, res, tsi, slen,
                                                           QW, W_slot, b_slot, res_sf);
}